// Round 2
// baseline (328.075 us; speedup 1.0000x reference)
//
#include <hip/hip_runtime.h>

typedef __attribute__((ext_vector_type(8))) short bfrag;
typedef __attribute__((ext_vector_type(4))) float ffrag;

#define MFMA16(a, b, c) __builtin_amdgcn_mfma_f32_16x16x32_bf16((a), (b), (c), 0, 0, 0)

namespace {
constexpr int nB  = 32;
constexpr int nLC = 2048;
constexpr int nLQ = 128;
constexpr int nD  = 128;
constexpr int RS  = 8;     // split-K for column pass

// workspace byte offsets
constexpr size_t OFF_SBF = 0;                          // ushort [B][LC][LQ]  16,777,216 B
constexpr size_t OFF_TNP = 16777216;                   // float  [B][RS][D][LQ] 16,777,216 B
constexpr size_t OFF_ZP  = OFF_TNP + 16777216;         // float  [B][RS][LQ]    131,072 B
constexpr size_t OFF_BWS = OFF_ZP + 131072;            // ushort [B][256][LQ]  2,097,152 B
} // namespace

__device__ __forceinline__ unsigned short f2bf(float x) {
  unsigned u = __float_as_uint(x);
  u = (u + 0x7fffu + ((u >> 16) & 1u)) >> 16;
  return (unsigned short)u;
}
__device__ __forceinline__ float bf2f(unsigned short h) {
  return __uint_as_float(((unsigned)h) << 16);
}

// ---------------------------------------------------------------------------
// k0_qt: B'[b][n=d][j] = bf16(Q[b][j][d])  (n < 128 half of the B' matrix)
// ---------------------------------------------------------------------------
__global__ __launch_bounds__(256) void k0_qt(
    const float* __restrict__ Q, unsigned short* __restrict__ Bws)
{
  __shared__ float Ql[128][132];
  const int t = threadIdx.x, b = blockIdx.x;
  {
    const int j = t >> 1, c0 = (t & 1) * 64;
    const float4* src = (const float4*)(Q + ((size_t)(b * nLQ + j)) * nD + c0);
    float4* dst = (float4*)&Ql[j][c0];
    #pragma unroll
    for (int u = 0; u < 16; ++u) dst[u] = src[u];
  }
  __syncthreads();
  {
    const int d = t >> 1, j0 = (t & 1) * 64;
    uint4 hq[8];
    unsigned short* h = (unsigned short*)hq;
    #pragma unroll
    for (int u = 0; u < 64; ++u) h[u] = f2bf(Ql[j0 + u][d]);
    uint4* dst = (uint4*)(Bws + ((size_t)(b * 256 + d)) * nLQ + j0);
    #pragma unroll
    for (int u = 0; u < 8; ++u) dst[u] = hq[u];
  }
}

// ---------------------------------------------------------------------------
// k1: S[b,i,j] = Cw1[i] + Qw2[j] + sum_d (C*w3)[i,d]*Q[j,d]  -> Sbf (bf16)
// MFMA: A = bf16(C*w3) [i][d], B = bf16(Q) [j][d]  (both K-contiguous)
// ---------------------------------------------------------------------------
__global__ __launch_bounds__(256) void k1_scores(
    const float* __restrict__ C, const float* __restrict__ Q,
    const float* __restrict__ w, unsigned short* __restrict__ Sbf)
{
  __shared__ unsigned short Al[64][136];   // bf16(C*w3), reused for Sbf staging
  __shared__ unsigned short Bl[128][136];  // bf16(Q)
  __shared__ float wl[384];
  __shared__ float cw1l[64];
  __shared__ float qw2l[128];

  const int t  = threadIdx.x;
  const int b  = blockIdx.y;
  const int i0 = blockIdx.x * 64;

  for (int idx = t; idx < 384; idx += 256) wl[idx] = w[idx];
  __syncthreads();

  // stage C tile: row = t>>2 (64 rows), 32 d-elements each
  {
    const int row = t >> 2, c0 = (t & 3) * 32;
    const float4* crow = (const float4*)(C + ((size_t)(b * nLC + i0 + row)) * nD + c0);
    float cw1p = 0.f;
    #pragma unroll
    for (int u = 0; u < 4; ++u) {
      float4 v0 = crow[u * 2], v1 = crow[u * 2 + 1];
      const int d = c0 + u * 8;
      cw1p += v0.x * wl[d + 0] + v0.y * wl[d + 1] + v0.z * wl[d + 2] + v0.w * wl[d + 3]
            + v1.x * wl[d + 4] + v1.y * wl[d + 5] + v1.z * wl[d + 6] + v1.w * wl[d + 7];
      uint4 pk;
      unsigned short* ph = (unsigned short*)&pk;
      ph[0] = f2bf(v0.x * wl[256 + d + 0]); ph[1] = f2bf(v0.y * wl[256 + d + 1]);
      ph[2] = f2bf(v0.z * wl[256 + d + 2]); ph[3] = f2bf(v0.w * wl[256 + d + 3]);
      ph[4] = f2bf(v1.x * wl[256 + d + 4]); ph[5] = f2bf(v1.y * wl[256 + d + 5]);
      ph[6] = f2bf(v1.z * wl[256 + d + 6]); ph[7] = f2bf(v1.w * wl[256 + d + 7]);
      *(uint4*)&Al[row][d] = pk;
    }
    cw1p += __shfl_xor(cw1p, 1);
    cw1p += __shfl_xor(cw1p, 2);
    if ((t & 3) == 0) cw1l[row] = cw1p;
  }
  // stage Q: row j = t>>1 (128 rows), 64 d-elements each
  {
    const int j = t >> 1, c0 = (t & 1) * 64;
    const float4* qrow = (const float4*)(Q + ((size_t)(b * nLQ + j)) * nD + c0);
    float qp = 0.f;
    #pragma unroll
    for (int u = 0; u < 8; ++u) {
      float4 v0 = qrow[u * 2], v1 = qrow[u * 2 + 1];
      const int d = c0 + u * 8;
      qp += v0.x * wl[128 + d + 0] + v0.y * wl[128 + d + 1] + v0.z * wl[128 + d + 2] + v0.w * wl[128 + d + 3]
          + v1.x * wl[128 + d + 4] + v1.y * wl[128 + d + 5] + v1.z * wl[128 + d + 6] + v1.w * wl[128 + d + 7];
      uint4 pk;
      unsigned short* ph = (unsigned short*)&pk;
      ph[0] = f2bf(v0.x); ph[1] = f2bf(v0.y); ph[2] = f2bf(v0.z); ph[3] = f2bf(v0.w);
      ph[4] = f2bf(v1.x); ph[5] = f2bf(v1.y); ph[6] = f2bf(v1.z); ph[7] = f2bf(v1.w);
      *(uint4*)&Bl[j][d] = pk;
    }
    qp += __shfl_xor(qp, 1);
    if ((t & 1) == 0) qw2l[j] = qp;
  }
  __syncthreads();

  const int lane = t & 63, wv = t >> 6;
  const int lr = lane & 15, lk = lane >> 4;
  const int wr = wv * 16;

  ffrag acc[8];
  #pragma unroll
  for (int f = 0; f < 8; ++f) acc[f] = (ffrag){0.f, 0.f, 0.f, 0.f};

  #pragma unroll
  for (int ks = 0; ks < 4; ++ks) {
    bfrag a = *(const bfrag*)&Al[wr + lr][ks * 32 + lk * 8];
    #pragma unroll
    for (int f = 0; f < 8; ++f) {
      bfrag bb = *(const bfrag*)&Bl[f * 16 + lr][ks * 32 + lk * 8];
      acc[f] = MFMA16(a, bb, acc[f]);
    }
  }

  // epilogue: S = acc + cw1[row] + qw2[col]; round to bf16
  unsigned short sh[8][4];
  const float cwr0 = cw1l[wr + lk * 4 + 0];
  const float cwr1 = cw1l[wr + lk * 4 + 1];
  const float cwr2 = cw1l[wr + lk * 4 + 2];
  const float cwr3 = cw1l[wr + lk * 4 + 3];
  #pragma unroll
  for (int f = 0; f < 8; ++f) {
    const float qw = qw2l[f * 16 + lr];
    sh[f][0] = f2bf(acc[f][0] + cwr0 + qw);
    sh[f][1] = f2bf(acc[f][1] + cwr1 + qw);
    sh[f][2] = f2bf(acc[f][2] + cwr2 + qw);
    sh[f][3] = f2bf(acc[f][3] + cwr3 + qw);
  }
  __syncthreads();   // all MFMA reads of Al done -> reuse Al for S staging
  #pragma unroll
  for (int f = 0; f < 8; ++f) {
    #pragma unroll
    for (int r = 0; r < 4; ++r)
      Al[wr + lk * 4 + r][f * 16 + lr] = sh[f][r];
  }
  __syncthreads();
  {
    const int i = t >> 2, c0 = (t & 3) * 32;
    uint4* dst = (uint4*)(Sbf + ((size_t)(b * nLC + i0 + i)) * nLQ + c0);
    const uint4* src = (const uint4*)&Al[i][c0];
    #pragma unroll
    for (int u = 0; u < 4; ++u) dst[u] = src[u];
  }
}

// ---------------------------------------------------------------------------
// k3: per (b, rs): E = (cmask? 0 : exp(S)); Tnp_t[b][rs][d][j] = (E^T C)^T;
//     Zp[b][rs][j] = sum_i E[i][j]
// ---------------------------------------------------------------------------
__global__ __launch_bounds__(256) void k3_colpass(
    const float* __restrict__ C, const float* __restrict__ cmask,
    const unsigned short* __restrict__ Sbf,
    float* __restrict__ Tnp, float* __restrict__ Zp)
{
  __shared__ float smem[16896];  // 67,584 B
  unsigned short* Ea = (unsigned short*)smem;             // [128][40] bf16 E^T chunk
  unsigned short* Ct = ((unsigned short*)smem) + 128 * 40; // [128][40] bf16 C^T chunk
  float* Tf = smem;                                        // [128][132] f32 (epilogue)

  const int t  = threadIdx.x;
  const int b  = blockIdx.y, rs = blockIdx.x;
  const int i0 = rs * 256;
  const int lane = t & 63, wv = t >> 6;
  const int lr = lane & 15, lk = lane >> 4;
  const int wj = wv * 32;

  ffrag acc[2][8];
  #pragma unroll
  for (int rb = 0; rb < 2; ++rb)
    #pragma unroll
    for (int f = 0; f < 8; ++f) acc[rb][f] = (ffrag){0.f, 0.f, 0.f, 0.f};
  float zacc = 0.f;

  const int si = t >> 3;           // staging row 0..31
  const int sj = (t & 7) * 16;     // staging col 0..112

  for (int ch = 0; ch < 8; ++ch) {
    const int gi0 = i0 + ch * 32;
    __syncthreads();
    // stage E^T chunk (transpose write)
    {
      const int gi = gi0 + si;
      const float cmv = cmask[b * nLC + gi];
      uint4 hq[2];
      const uint4* src = (const uint4*)(Sbf + ((size_t)(b * nLC + gi)) * nLQ + sj);
      hq[0] = src[0]; hq[1] = src[1];
      const unsigned short* hv = (const unsigned short*)hq;
      if (cmv != 0.f) {
        #pragma unroll
        for (int u = 0; u < 16; ++u) Ea[(sj + u) * 40 + si] = 0;
      } else {
        #pragma unroll
        for (int u = 0; u < 16; ++u)
          Ea[(sj + u) * 40 + si] = f2bf(__expf(bf2f(hv[u])));
      }
    }
    // stage C^T chunk (transpose write)
    {
      const float4* src = (const float4*)(C + ((size_t)(b * nLC + gi0 + si)) * nD + sj);
      #pragma unroll
      for (int u4 = 0; u4 < 4; ++u4) {
        float4 v = src[u4];
        Ct[(sj + u4 * 4 + 0) * 40 + si] = f2bf(v.x);
        Ct[(sj + u4 * 4 + 1) * 40 + si] = f2bf(v.y);
        Ct[(sj + u4 * 4 + 2) * 40 + si] = f2bf(v.z);
        Ct[(sj + u4 * 4 + 3) * 40 + si] = f2bf(v.w);
      }
    }
    __syncthreads();
    // Z partial (threads 0..127, one j each)
    if (t < 128) {
      const uint4* er = (const uint4*)&Ea[t * 40];
      #pragma unroll
      for (int u4 = 0; u4 < 4; ++u4) {
        uint4 vv = er[u4];
        const unsigned short* hh = (const unsigned short*)&vv;
        #pragma unroll
        for (int u = 0; u < 8; ++u) zacc += bf2f(hh[u]);
      }
    }
    // MFMA: one K=32 step
    bfrag a0 = *(const bfrag*)&Ea[(wj + lr) * 40 + lk * 8];
    bfrag a1 = *(const bfrag*)&Ea[(wj + 16 + lr) * 40 + lk * 8];
    #pragma unroll
    for (int f = 0; f < 8; ++f) {
      bfrag bb = *(const bfrag*)&Ct[(f * 16 + lr) * 40 + lk * 8];
      acc[0][f] = MFMA16(a0, bb, acc[0][f]);
      acc[1][f] = MFMA16(a1, bb, acc[1][f]);
    }
  }
  __syncthreads();
  // stage transposed result Tf[d][j] (f32x4 along j)
  #pragma unroll
  for (int rb = 0; rb < 2; ++rb)
    #pragma unroll
    for (int f = 0; f < 8; ++f)
      *(ffrag*)&Tf[(f * 16 + lr) * 132 + wj + rb * 16 + lk * 4] = acc[rb][f];
  __syncthreads();
  {
    const int d = t >> 1, j0 = (t & 1) * 64;
    float4* dst = (float4*)(Tnp + (((size_t)(b * RS + rs)) * nD + d) * nLQ + j0);
    const float4* src = (const float4*)&Tf[d * 132 + j0];
    #pragma unroll
    for (int u = 0; u < 16; ++u) dst[u] = src[u];
  }
  if (t < 128) Zp[((size_t)(b * RS + rs)) * nLQ + t] = zacc;
}

// ---------------------------------------------------------------------------
// k3b: B'[b][128+d][j] = bf16( (sum_rs Tnp[b][rs][d][j]) / Z[j] )
// ---------------------------------------------------------------------------
__global__ __launch_bounds__(256) void k3b_reduce(
    const float* __restrict__ Tnp, const float* __restrict__ Zp,
    unsigned short* __restrict__ Bws)
{
  __shared__ float zinv[128];
  const int t = threadIdx.x;
  const int b = blockIdx.y, dc = blockIdx.x;
  if (t < 128) {
    float z = 0.f;
    #pragma unroll
    for (int rs = 0; rs < RS; ++rs) z += Zp[((size_t)(b * RS + rs)) * nLQ + t];
    zinv[t] = (z > 0.f) ? 1.f / z : 0.f;
  }
  __syncthreads();
  const int d = dc * 8 + (t >> 5), j0 = (t & 31) * 4;
  float4 s = make_float4(0.f, 0.f, 0.f, 0.f);
  #pragma unroll
  for (int rs = 0; rs < RS; ++rs) {
    float4 v = *(const float4*)(Tnp + (((size_t)(b * RS + rs)) * nD + d) * nLQ + j0);
    s.x += v.x; s.y += v.y; s.z += v.z; s.w += v.w;
  }
  uint2 pk;
  unsigned short* ph = (unsigned short*)&pk;
  ph[0] = f2bf(s.x * zinv[j0 + 0]);
  ph[1] = f2bf(s.y * zinv[j0 + 1]);
  ph[2] = f2bf(s.z * zinv[j0 + 2]);
  ph[3] = f2bf(s.w * zinv[j0 + 3]);
  *(uint2*)(Bws + ((size_t)(b * 256 + 128 + d)) * nLQ + j0) = pk;
}

// ---------------------------------------------------------------------------
// k4: S1 = row-softmax(S, qmask); [A|Bt] = S1 @ B'; out = [C, A, C*A, C*Bt]
// ---------------------------------------------------------------------------
__global__ __launch_bounds__(256) void k4_out(
    const float* __restrict__ C, const float* __restrict__ qmask,
    const unsigned short* __restrict__ Sbf, const unsigned short* __restrict__ Bws,
    float* __restrict__ out)
{
  __shared__ float smem[16896];  // 67,584 B (union)
  __shared__ float qml[128];
  unsigned short* S1l = (unsigned short*)smem;               // [64][136]
  unsigned short* Bl  = ((unsigned short*)smem) + 64 * 136;  // [128][136]
  float* Af = smem;                                          // [64][264] (epilogue)

  const int t  = threadIdx.x;
  const int b  = blockIdx.y;
  const int i0 = blockIdx.x * 64;

  if (t < 128) qml[t] = qmask[b * nLQ + t];
  __syncthreads();

  // S1 staging: row softmax (4 threads per row)
  {
    const int i = t >> 2, c0 = (t & 3) * 32;
    uint4 hq[4];
    const uint4* src = (const uint4*)(Sbf + ((size_t)(b * nLC + i0 + i)) * nLQ + c0);
    hq[0] = src[0]; hq[1] = src[1]; hq[2] = src[2]; hq[3] = src[3];
    const unsigned short* hv = (const unsigned short*)hq;
    float e[32];
    float rsum = 0.f;
    #pragma unroll
    for (int u = 0; u < 32; ++u) {
      const float p = (qml[c0 + u] != 0.f) ? 0.f : __expf(bf2f(hv[u]));
      e[u] = p;
      rsum += p;
    }
    rsum += __shfl_xor(rsum, 1);
    rsum += __shfl_xor(rsum, 2);
    const float rinv = (rsum > 0.f) ? 1.f / rsum : 0.f;
    uint4 oq[4];
    unsigned short* oh = (unsigned short*)oq;
    #pragma unroll
    for (int u = 0; u < 32; ++u) oh[u] = f2bf(e[u] * rinv);
    uint4* dst = (uint4*)&S1l[i * 136 + c0];
    dst[0] = oq[0]; dst[1] = oq[1]; dst[2] = oq[2]; dst[3] = oq[3];
  }

  const int lane = t & 63, wv = t >> 6;
  const int lr = lane & 15, lk = lane >> 4;
  const int wr = wv * 16;

  ffrag acc[2][8];
  #pragma unroll
  for (int nh = 0; nh < 2; ++nh)
    #pragma unroll
    for (int f = 0; f < 8; ++f) acc[nh][f] = (ffrag){0.f, 0.f, 0.f, 0.f};

  for (int nh = 0; nh < 2; ++nh) {
    __syncthreads();  // S1l staged (first iter) / previous Bl reads done
    {
      const int n = t >> 1, j0 = (t & 1) * 64;
      const uint4* src = (const uint4*)(Bws + ((size_t)(b * 256 + nh * 128 + n)) * nLQ + j0);
      uint4* dst = (uint4*)&Bl[n * 136 + j0];
      #pragma unroll
      for (int u = 0; u < 8; ++u) dst[u] = src[u];
    }
    __syncthreads();
    bfrag a[4];
    #pragma unroll
    for (int ks = 0; ks < 4; ++ks)
      a[ks] = *(const bfrag*)&S1l[(wr + lr) * 136 + ks * 32 + lk * 8];
    #pragma unroll
    for (int f = 0; f < 8; ++f) {
      #pragma unroll
      for (int ks = 0; ks < 4; ++ks) {
        bfrag bb = *(const bfrag*)&Bl[(f * 16 + lr) * 136 + ks * 32 + lk * 8];
        acc[nh][f] = MFMA16(a[ks], bb, acc[nh][f]);
      }
    }
  }
  __syncthreads();
  // stage accumulators to Af[i][n]
  #pragma unroll
  for (int nh = 0; nh < 2; ++nh)
    #pragma unroll
    for (int f = 0; f < 8; ++f) {
      const int col = nh * 128 + f * 16 + lr;
      #pragma unroll
      for (int r = 0; r < 4; ++r)
        Af[(wr + lk * 4 + r) * 264 + col] = acc[nh][f][r];
    }
  __syncthreads();
  // fused epilogue
  {
    const int i = t >> 2, c0 = (t & 3) * 32;
    const float4* crow = (const float4*)(C + ((size_t)(b * nLC + i0 + i)) * nD + c0);
    float* orow = out + ((size_t)(b * nLC + i0 + i)) * (4 * nD);
    #pragma unroll
    for (int u = 0; u < 8; ++u) {
      float4 cv = crow[u];
      float4 av = *(const float4*)&Af[i * 264 + c0 + u * 4];
      float4 bv = *(const float4*)&Af[i * 264 + 128 + c0 + u * 4];
      *(float4*)(orow + c0 + u * 4) = cv;
      *(float4*)(orow + 128 + c0 + u * 4) = av;
      *(float4*)(orow + 256 + c0 + u * 4) =
          make_float4(cv.x * av.x, cv.y * av.y, cv.z * av.z, cv.w * av.w);
      *(float4*)(orow + 384 + c0 + u * 4) =
          make_float4(cv.x * bv.x, cv.y * bv.y, cv.z * bv.z, cv.w * bv.w);
    }
  }
}

// ---------------------------------------------------------------------------
extern "C" void kernel_launch(void* const* d_in, const int* in_sizes, int n_in,
                              void* d_out, int out_size, void* d_ws, size_t ws_size,
                              hipStream_t stream)
{
  (void)in_sizes; (void)n_in; (void)out_size; (void)ws_size;
  const float* C     = (const float*)d_in[0];
  const float* Q     = (const float*)d_in[1];
  const float* cmask = (const float*)d_in[2];
  const float* qmask = (const float*)d_in[3];
  const float* w     = (const float*)d_in[4];
  float* out = (float*)d_out;
  char* wsb  = (char*)d_ws;

  unsigned short* Sbf = (unsigned short*)(wsb + OFF_SBF);
  float*          Tnp = (float*)(wsb + OFF_TNP);
  float*          Zp  = (float*)(wsb + OFF_ZP);
  unsigned short* Bws = (unsigned short*)(wsb + OFF_BWS);

  k0_qt     <<<dim3(nB),      256, 0, stream>>>(Q, Bws);
  k1_scores <<<dim3(32, nB),  256, 0, stream>>>(C, Q, w, Sbf);
  k3_colpass<<<dim3(RS, nB),  256, 0, stream>>>(C, cmask, Sbf, Tnp, Zp);
  k3b_reduce<<<dim3(16, nB),  256, 0, stream>>>(Tnp, Zp, Bws);
  k4_out    <<<dim3(32, nB),  256, 0, stream>>>(C, qmask, Sbf, Bws, out);
}

// Round 4
// 248.626 us; speedup vs baseline: 1.3196x; 1.3196x over previous
//
#include <hip/hip_runtime.h>

typedef __attribute__((ext_vector_type(8))) short bfrag;
typedef __attribute__((ext_vector_type(4))) float ffrag;

#define MFMA16(a, b, c) __builtin_amdgcn_mfma_f32_16x16x32_bf16((a), (b), (c), 0, 0, 0)

namespace {
constexpr int nB  = 32;
constexpr int nLC = 2048;
constexpr int nLQ = 128;
constexpr int nD  = 128;

// workspace byte offsets (total 50 MiB = 52,428,800 B; proven floor 53,100,544 B)
constexpr size_t OFF_EBF = 0;                    // ushort [B][LC][LQ]   16 MiB (unmasked exp(S))
constexpr size_t OFF_ET  = 16777216;             // ushort [B][LQ][LC]   16 MiB (cmask-masked exp(S), transposed)
constexpr size_t OFF_CT  = 33554432;             // ushort [B][D][LC]    16 MiB (bf16 C^T)
constexpr size_t OFF_BWS = 50331648;             // ushort [B][256][LQ]   2 MiB ([Q^T ; T^T])
} // namespace

__device__ __forceinline__ unsigned short f2bf(float x) {
  unsigned u = __float_as_uint(x);
  u = (u + 0x7fffu + ((u >> 16) & 1u)) >> 16;
  return (unsigned short)u;
}
__device__ __forceinline__ float bf2f(unsigned short h) {
  return __uint_as_float(((unsigned)h) << 16);
}

// ---------------------------------------------------------------------------
// k0: Bws[b][d][j] = bf16(Q^T)   (d < 128 half of the B' matrix)
// ---------------------------------------------------------------------------
__global__ __launch_bounds__(256) void k0_qt(
    const float* __restrict__ Q, unsigned short* __restrict__ Bws)
{
  __shared__ float Ql[128 * 133];
  const int t = threadIdx.x, b = blockIdx.x;
  {
    const int j = t >> 1, half = (t & 1) * 64;
    const float4* qr = (const float4*)(Q + ((size_t)(b * nLQ + j)) * nD + half);
    #pragma unroll
    for (int u = 0; u < 16; ++u) {
      float4 v = qr[u];
      const int c = half + u * 4;
      Ql[j * 133 + c + 0] = v.x; Ql[j * 133 + c + 1] = v.y;
      Ql[j * 133 + c + 2] = v.z; Ql[j * 133 + c + 3] = v.w;
    }
  }
  __syncthreads();
  // Q^T flat write: [128 d][128 j] bf16, 16B per lane per iter (1KB/wave-instr)
  #pragma unroll
  for (int it = 0; it < 8; ++it) {
    const int d = it * 16 + (t >> 4), j0 = (t & 15) * 8;
    unsigned short hq[8];
    #pragma unroll
    for (int u = 0; u < 8; ++u) hq[u] = f2bf(Ql[(j0 + u) * 133 + d]);
    *(uint4*)(Bws + ((size_t)(b * 256 + d)) * nLQ + j0) = *(const uint4*)hq;
  }
}

// ---------------------------------------------------------------------------
// k1: S = Cw1 (+) Qw2 + (C*w3)@Q^T ; E = exp(S)
//     Ebf[i][j] = E ; Et[j][i] = E*(1-cmask[i]) ; Ct[d][i] = bf16(C^T)
// ---------------------------------------------------------------------------
__global__ __launch_bounds__(256) void k1_scores(
    const float* __restrict__ C, const float* __restrict__ Q,
    const float* __restrict__ cmask, const float* __restrict__ w,
    unsigned short* __restrict__ Ebf, unsigned short* __restrict__ Et,
    unsigned short* __restrict__ Ct)
{
  // arena: Al [64][136] | Bl [128][136] (Ctl [128][74] overlays Bl post-MFMA) | Etl [128][66]
  __shared__ __align__(16) char arena[69120];
  unsigned short* Al  = (unsigned short*)arena;            // 17,408 B
  unsigned short* Bl  = (unsigned short*)(arena + 17408);  // 34,816 B
  unsigned short* Ctl = (unsigned short*)(arena + 17408);  // 18,944 B (overlay)
  unsigned short* Etl = (unsigned short*)(arena + 52224);  // 16,896 B
  __shared__ float wl[384];
  __shared__ float cw1l[64];
  __shared__ float qw2l[128];

  const int t  = threadIdx.x;
  const int b  = blockIdx.y;
  const int i0 = blockIdx.x * 64;

  for (int idx = t; idx < 384; idx += 256) wl[idx] = w[idx];
  __syncthreads();   // wl visible to all waves (round-3 bug: this was missing)

  // stage A = bf16(C*w3), cw1 partial
  {
    const int row = t >> 2, c0 = (t & 3) * 32;
    const float4* crow = (const float4*)(C + ((size_t)(b * nLC + i0 + row)) * nD + c0);
    float cw1p = 0.f;
    unsigned short ap[32];
    #pragma unroll
    for (int u = 0; u < 8; ++u) {
      float4 v = crow[u];
      const int d = c0 + u * 4;
      cw1p += v.x * wl[d + 0] + v.y * wl[d + 1] + v.z * wl[d + 2] + v.w * wl[d + 3];
      ap[u * 4 + 0] = f2bf(v.x * wl[256 + d + 0]);
      ap[u * 4 + 1] = f2bf(v.y * wl[256 + d + 1]);
      ap[u * 4 + 2] = f2bf(v.z * wl[256 + d + 2]);
      ap[u * 4 + 3] = f2bf(v.w * wl[256 + d + 3]);
    }
    uint4* dst = (uint4*)&Al[row * 136 + c0];
    const uint4* sv = (const uint4*)ap;
    #pragma unroll
    for (int u = 0; u < 4; ++u) dst[u] = sv[u];
    cw1p += __shfl_xor(cw1p, 1);
    cw1p += __shfl_xor(cw1p, 2);
    if ((t & 3) == 0) cw1l[row] = cw1p;
  }
  // stage B = bf16(Q), qw2 partial
  {
    const int j = t >> 1, half = (t & 1) * 64;
    const float4* qr = (const float4*)(Q + ((size_t)(b * nLQ + j)) * nD + half);
    float qp = 0.f;
    unsigned short hq[64];
    #pragma unroll
    for (int u = 0; u < 16; ++u) {
      float4 v = qr[u];
      const int d = half + u * 4;
      qp += v.x * wl[128 + d + 0] + v.y * wl[128 + d + 1]
          + v.z * wl[128 + d + 2] + v.w * wl[128 + d + 3];
      hq[u * 4 + 0] = f2bf(v.x); hq[u * 4 + 1] = f2bf(v.y);
      hq[u * 4 + 2] = f2bf(v.z); hq[u * 4 + 3] = f2bf(v.w);
    }
    uint4* dst = (uint4*)&Bl[j * 136 + half];
    const uint4* sv = (const uint4*)hq;
    #pragma unroll
    for (int u = 0; u < 8; ++u) dst[u] = sv[u];
    qp += __shfl_xor(qp, 1);
    if ((t & 1) == 0) qw2l[j] = qp;
  }
  __syncthreads();

  const int lane = t & 63, wv = t >> 6;
  const int lr = lane & 15, lk = lane >> 4;
  const int wr = wv * 16;

  bfrag a[4];
  #pragma unroll
  for (int ks = 0; ks < 4; ++ks)
    a[ks] = *(const bfrag*)&Al[(wr + lr) * 136 + ks * 32 + lk * 8];

  ffrag acc[8];
  #pragma unroll
  for (int f = 0; f < 8; ++f) acc[f] = (ffrag){0.f, 0.f, 0.f, 0.f};

  #pragma unroll
  for (int f = 0; f < 8; ++f) {
    #pragma unroll
    for (int ks = 0; ks < 4; ++ks) {
      bfrag bb = *(const bfrag*)&Bl[(f * 16 + lr) * 136 + ks * 32 + lk * 8];
      acc[f] = MFMA16(a[ks], bb, acc[f]);
    }
  }

  // E = exp(acc + cw1 + qw2); Em = E * (1-cmask)
  float cwv[4], cmv[4];
  #pragma unroll
  for (int r = 0; r < 4; ++r) {
    cwv[r] = cw1l[wr + lk * 4 + r];
    cmv[r] = cmask[b * nLC + i0 + wr + lk * 4 + r];
  }
  float ev[8][4], em[8][4];
  #pragma unroll
  for (int f = 0; f < 8; ++f) {
    const float qw = qw2l[f * 16 + lr];
    #pragma unroll
    for (int r = 0; r < 4; ++r) {
      const float e = __expf(acc[f][r] + cwv[r] + qw);
      ev[f][r] = e;
      em[f][r] = (cmv[r] != 0.f) ? 0.f : e;
    }
  }
  __syncthreads();   // Al a-frags & Bl b-frags consumed -> reuse Al (E) and Bl (Ctl)

  #pragma unroll
  for (int f = 0; f < 8; ++f) {
    #pragma unroll
    for (int r = 0; r < 4; ++r) {
      Al[(wr + lk * 4 + r) * 136 + f * 16 + lr]  = f2bf(ev[f][r]);
      Etl[(f * 16 + lr) * 66 + wr + lk * 4 + r]  = f2bf(em[f][r]);
    }
  }
  // C^T staging (re-read C, lane-granular d)
  {
    const int dd = t & 127, ihalf = (t >> 7) * 32;
    #pragma unroll
    for (int v = 0; v < 32; ++v) {
      const int i = ihalf + v;
      Ctl[dd * 74 + i] = f2bf(C[((size_t)(b * nLC + i0 + i)) * nD + dd]);
    }
  }
  __syncthreads();

  // flat coalesced writes (each wave instruction = contiguous 1KB)
  #pragma unroll
  for (int it = 0; it < 4; ++it) {
    const int i = it * 16 + (t >> 4), j0 = (t & 15) * 8;
    *(uint4*)(Ebf + ((size_t)(b * nLC + i0 + i)) * nLQ + j0)
        = *(const uint4*)&Al[i * 136 + j0];
  }
  const uint* etp = (const uint*)Etl;
  #pragma unroll
  for (int it = 0; it < 4; ++it) {
    const int j = it * 32 + (t >> 3), io = (t & 7) * 8;
    const int bd = j * 33 + (t & 7) * 4;
    uint4 val = make_uint4(etp[bd], etp[bd + 1], etp[bd + 2], etp[bd + 3]);
    *(uint4*)(Et + ((size_t)(b * nLQ + j)) * nLC + i0 + io) = val;
  }
  const uint* ctp = (const uint*)Ctl;
  #pragma unroll
  for (int it = 0; it < 4; ++it) {
    const int d = it * 32 + (t >> 3), io = (t & 7) * 8;
    const int bd = d * 37 + (t & 7) * 4;
    uint4 val = make_uint4(ctp[bd], ctp[bd + 1], ctp[bd + 2], ctp[bd + 3]);
    *(uint4*)(Ct + ((size_t)(b * nD + d)) * nLC + i0 + io) = val;
  }
}

// ---------------------------------------------------------------------------
// k3: T^T[d][j] = (sum_i Et[j][i]*Ct[d][i]) / Z[j],  Z via MFMA vs ones.
//     writes Bws[b][128+d][j].  Full K=2048 per block -> no partials.
//     grid: (dt 8 x jh 2, B), block 128 threads (2 waves).
// ---------------------------------------------------------------------------
__global__ __launch_bounds__(128) void k3_colpass(
    const unsigned short* __restrict__ Et, const unsigned short* __restrict__ Ct,
    unsigned short* __restrict__ Bws)
{
  __shared__ unsigned short Tf[16 * 72];
  const int t  = threadIdx.x;
  const int dt = blockIdx.x & 7, jh = blockIdx.x >> 3;
  const int b  = blockIdx.y;
  const int lane = t & 63, wv = t >> 6;
  const int lr = lane & 15, lk = lane >> 4;
  const int wj = jh * 64 + wv * 32;

  bfrag ones;
  #pragma unroll
  for (int e = 0; e < 8; ++e) ones[e] = (short)0x3F80;

  ffrag acc[2], accz[2];
  #pragma unroll
  for (int mt = 0; mt < 2; ++mt) {
    acc[mt]  = (ffrag){0.f, 0.f, 0.f, 0.f};
    accz[mt] = (ffrag){0.f, 0.f, 0.f, 0.f};
  }

  const unsigned short* arow0 = Et + ((size_t)(b * nLQ + wj + lr)) * nLC;
  const unsigned short* arow1 = Et + ((size_t)(b * nLQ + wj + 16 + lr)) * nLC;
  const unsigned short* brow  = Ct + ((size_t)(b * nD + dt * 16 + lr)) * nLC;

  #pragma unroll 4
  for (int ks = 0; ks < 64; ++ks) {
    const int koff = ks * 32 + lk * 8;
    bfrag a0 = *(const bfrag*)(arow0 + koff);
    bfrag a1 = *(const bfrag*)(arow1 + koff);
    bfrag bb = *(const bfrag*)(brow + koff);
    acc[0]  = MFMA16(a0, bb,   acc[0]);
    acc[1]  = MFMA16(a1, bb,   acc[1]);
    accz[0] = MFMA16(a0, ones, accz[0]);
    accz[1] = MFMA16(a1, ones, accz[1]);
  }

  // scale by 1/Z, stage transposed [d-local][j-local]
  #pragma unroll
  for (int mt = 0; mt < 2; ++mt) {
    #pragma unroll
    for (int r = 0; r < 4; ++r) {
      const float z = accz[mt][r];
      const float zi = (z != 0.f) ? 1.f / z : 0.f;
      const int jl = wv * 32 + mt * 16 + lk * 4 + r;
      Tf[lr * 72 + jl] = f2bf(acc[mt][r] * zi);
    }
  }
  __syncthreads();
  {
    const int d = t >> 3, jo = (t & 7) * 8;
    const uint* p = (const uint*)Tf;
    const int bd = d * 36 + (t & 7) * 4;
    uint4 val = make_uint4(p[bd], p[bd + 1], p[bd + 2], p[bd + 3]);
    *(uint4*)(Bws + ((size_t)(b * 256 + 128 + dt * 16 + d)) * nLQ + jh * 64 + jo) = val;
  }
}

// ---------------------------------------------------------------------------
// k4: S1 = qmask-row-softmax from Ebf; [A|Bt] = S1 @ Bws; out=[C,A,C*A,C*Bt]
// ---------------------------------------------------------------------------
__global__ __launch_bounds__(256) void k4_out(
    const float* __restrict__ C, const float* __restrict__ qmask,
    const unsigned short* __restrict__ Ebf, const unsigned short* __restrict__ Bws,
    float* __restrict__ out)
{
  __shared__ __align__(16) char arena[66560];  // S1l [64][136] ush  |  Af [64][260] f32
  __shared__ float qml[128];
  unsigned short* S1l = (unsigned short*)arena;
  float* Af = (float*)arena;

  const int t  = threadIdx.x;
  const int b  = blockIdx.y;
  const int i0 = blockIdx.x * 64;

  if (t < 128) qml[t] = 1.0f - qmask[b * nLQ + t];
  __syncthreads();

  // S1 row-softmax (Ebf already holds exp(S))
  {
    const int i = t >> 2, c0 = (t & 3) * 32;
    uint4 hq[4];
    const uint4* src = (const uint4*)(Ebf + ((size_t)(b * nLC + i0 + i)) * nLQ + c0);
    hq[0] = src[0]; hq[1] = src[1]; hq[2] = src[2]; hq[3] = src[3];
    const unsigned short* hv = (const unsigned short*)hq;
    float ev[32];
    float rsum = 0.f;
    #pragma unroll
    for (int u = 0; u < 32; ++u) {
      ev[u] = bf2f(hv[u]) * qml[c0 + u];
      rsum += ev[u];
    }
    rsum += __shfl_xor(rsum, 1);
    rsum += __shfl_xor(rsum, 2);
    const float rinv = (rsum > 0.f) ? 1.f / rsum : 0.f;
    unsigned short oh[32];
    #pragma unroll
    for (int u = 0; u < 32; ++u) oh[u] = f2bf(ev[u] * rinv);
    uint4* dst = (uint4*)&S1l[i * 136 + c0];
    const uint4* sv = (const uint4*)oh;
    dst[0] = sv[0]; dst[1] = sv[1]; dst[2] = sv[2]; dst[3] = sv[3];
  }
  __syncthreads();

  const int lane = t & 63, wv = t >> 6;
  const int lr = lane & 15, lk = lane >> 4;
  const int wr = wv * 16;

  bfrag a[4];
  #pragma unroll
  for (int ks = 0; ks < 4; ++ks)
    a[ks] = *(const bfrag*)&S1l[(wr + lr) * 136 + ks * 32 + lk * 8];

  ffrag acc[16];
  #pragma unroll
  for (int nt = 0; nt < 16; ++nt) acc[nt] = (ffrag){0.f, 0.f, 0.f, 0.f};

  const unsigned short* bwb = Bws + (size_t)b * 256 * nLQ;
  #pragma unroll
  for (int nt = 0; nt < 16; ++nt) {
    #pragma unroll
    for (int ks = 0; ks < 4; ++ks) {
      bfrag bb = *(const bfrag*)(bwb + (nt * 16 + lr) * nLQ + ks * 32 + lk * 8);
      acc[nt] = MFMA16(a[ks], bb, acc[nt]);
    }
  }
  __syncthreads();   // S1l reads done -> Af overlays arena

  #pragma unroll
  for (int nt = 0; nt < 16; ++nt) {
    #pragma unroll
    for (int r = 0; r < 4; ++r)
      Af[(wr + lk * 4 + r) * 260 + nt * 16 + lr] = acc[nt][r];
  }
  __syncthreads();

  // epilogue: wave w writes segment w; lane l covers d = 2l, 2l+1.
  // each wave store instruction = 512B contiguous; 4 waves tile the row.
  const int w = t >> 6, l = t & 63, d = 2 * l;
  const size_t orow0 = ((size_t)(b * nLC + i0)) * 512 + w * 128 + d;
  const size_t crow0 = ((size_t)(b * nLC + i0)) * nD + d;
  if (w == 0) {
    for (int i = 0; i < 64; ++i) {
      float2 cv = *(const float2*)(C + crow0 + (size_t)i * nD);
      *(float2*)(out + orow0 + (size_t)i * 512) = cv;
    }
  } else if (w == 1) {
    for (int i = 0; i < 64; ++i) {
      float2 av = make_float2(Af[i * 260 + d], Af[i * 260 + d + 1]);
      *(float2*)(out + orow0 + (size_t)i * 512) = av;
    }
  } else if (w == 2) {
    for (int i = 0; i < 64; ++i) {
      float2 cv = *(const float2*)(C + crow0 + (size_t)i * nD);
      float2 av = make_float2(Af[i * 260 + d], Af[i * 260 + d + 1]);
      *(float2*)(out + orow0 + (size_t)i * 512) = make_float2(cv.x * av.x, cv.y * av.y);
    }
  } else {
    for (int i = 0; i < 64; ++i) {
      float2 cv = *(const float2*)(C + crow0 + (size_t)i * nD);
      float2 bv = make_float2(Af[i * 260 + 128 + d], Af[i * 260 + 128 + d + 1]);
      *(float2*)(out + orow0 + (size_t)i * 512) = make_float2(cv.x * bv.x, cv.y * bv.y);
    }
  }
}

// ---------------------------------------------------------------------------
extern "C" void kernel_launch(void* const* d_in, const int* in_sizes, int n_in,
                              void* d_out, int out_size, void* d_ws, size_t ws_size,
                              hipStream_t stream)
{
  (void)in_sizes; (void)n_in; (void)out_size; (void)ws_size;
  const float* C     = (const float*)d_in[0];
  const float* Q     = (const float*)d_in[1];
  const float* cmask = (const float*)d_in[2];
  const float* qmask = (const float*)d_in[3];
  const float* w     = (const float*)d_in[4];
  float* out = (float*)d_out;
  char* wsb  = (char*)d_ws;

  unsigned short* Ebf = (unsigned short*)(wsb + OFF_EBF);
  unsigned short* Et  = (unsigned short*)(wsb + OFF_ET);
  unsigned short* Ct  = (unsigned short*)(wsb + OFF_CT);
  unsigned short* Bws = (unsigned short*)(wsb + OFF_BWS);

  k0_qt     <<<dim3(nB),      256, 0, stream>>>(Q, Bws);
  k1_scores <<<dim3(32, nB),  256, 0, stream>>>(C, Q, cmask, w, Ebf, Et, Ct);
  k3_colpass<<<dim3(16, nB),  128, 0, stream>>>(Et, Ct, Bws);
  k4_out    <<<dim3(32, nB),  256, 0, stream>>>(C, qmask, Ebf, Bws, out);
}